// Round 6
// baseline (1267.896 us; speedup 1.0000x reference)
//
#include <hip/hip_runtime.h>
#include <hip/hip_bf16.h>

// Grouped GEMM: E=16 experts, each [2048x1024] @ [1024x4096], fp32 in/out.
// Round 6:
//   Pass 1 (fused): A fp32->bf16 convert + W [K][N]->WT [N][K] bf16 transpose.
//   Pass 2 : persistent 256-block GEMM. 256x256 tile, BK=64, 8 waves (2Mx4N),
//            128 KiB LDS double buffer, involution swizzle (conflict-free),
//            8 phases/iter of 16 MFMA each with ONE-PHASE-AHEAD register
//            prefetch (counted lgkmcnt 4/8, never draining own reads),
//            counted vmcnt(2/2/2/4) with >=1.7-phase landing slack,
//            uniform k-tile stream across 8 output tiles per block
//            (staging + pipeline run through the per-tile epilogue).

#define E_NUM 16
#define M_PER_E 2048
#define K_DIM 1024
#define N_DIM 4096

#define A_ELEMS (E_NUM * M_PER_E * K_DIM)
#define W_ELEMS (E_NUM * K_DIM * N_DIM)
#define WS_NEEDED ((size_t)A_ELEMS * 2 + (size_t)W_ELEMS * 2)

typedef float  float4v  __attribute__((ext_vector_type(4)));
typedef float  f32x4    __attribute__((ext_vector_type(4)));
typedef short  bf16x8   __attribute__((ext_vector_type(8)));
typedef unsigned short ushort4v __attribute__((ext_vector_type(4)));
typedef unsigned short ushort8v __attribute__((ext_vector_type(8)));

__device__ __forceinline__ ushort4v cvt4_bf16(float4v f) {
    union { __bf16 h[4]; ushort4v u; } x;
#pragma unroll
    for (int j = 0; j < 4; ++j) x.h[j] = (__bf16)f[j];
    return x.u;
}

// ---------------- Pass 1: fused prepass ----------------
// blocks [0,16384): W transpose (64x64 tiles); blocks [16384,18432): A convert.
__global__ __launch_bounds__(256) void prepass_kernel(
    const float* __restrict__ A, const float* __restrict__ W,
    unsigned short* __restrict__ outA, unsigned short* __restrict__ outW)
{
    __shared__ __align__(16) float T[64 * 64];
    const int b = blockIdx.x;
    const int t = threadIdx.x;

    if (b < 16384) {
        const int nt = b & 63;
        const int kt = (b >> 6) & 15;
        const int e  = b >> 10;
        const float* Wb = W + ((size_t)e * K_DIM + (size_t)kt * 64) * N_DIM + nt * 64;

#pragma unroll
        for (int j = 0; j < 4; ++j) {
            int kl = (t >> 4) + j * 16;
            int n4 = t & 15;
            float4v v = *reinterpret_cast<const float4v*>(Wb + (size_t)kl * N_DIM + n4 * 4);
            int sp = n4 ^ ((kl >> 3) & 7);
            *reinterpret_cast<float4v*>(&T[kl * 64 + sp * 4]) = v;
        }
        __syncthreads();

#pragma unroll
        for (int c = 0; c < 2; ++c) {
            int nl = (t >> 3) + c * 32;
            int kc = t & 7;
            ushort8v v;
#pragma unroll
            for (int j = 0; j < 8; ++j) {
                int kl = kc * 8 + j;
                int sp = (nl >> 2) ^ kc;
                float f = T[kl * 64 + sp * 4 + (nl & 3)];
                union { __bf16 h; unsigned short u; } cv; cv.h = (__bf16)f;
                v[j] = cv.u;
            }
            unsigned short* dst = outW + ((size_t)e * N_DIM + (size_t)nt * 64 + nl) * K_DIM
                                  + (size_t)kt * 64 + kc * 8;
            *reinterpret_cast<ushort8v*>(dst) = v;
        }
    } else {
        const int n8 = A_ELEMS / 8;
        int idx = (b - 16384) * 256 + t;
        int stride = 2048 * 256;
        for (int i = idx; i < n8; i += stride) {
            float4v a = *reinterpret_cast<const float4v*>(A + (size_t)i * 8);
            float4v bb = *reinterpret_cast<const float4v*>(A + (size_t)i * 8 + 4);
            ushort8v v;
            ushort4v va = cvt4_bf16(a), vb = cvt4_bf16(bb);
#pragma unroll
            for (int j = 0; j < 4; ++j) { v[j] = va[j]; v[j + 4] = vb[j]; }
            *reinterpret_cast<ushort8v*>(outA + (size_t)i * 8) = v;
        }
    }
}

// ---------------- Pass 2: persistent 256^2 bf16 GEMM ----------------
#define GBM 256
#define GBN 256
#define GBK 64
#define NT_TOTAL 128   // 8 output tiles x 16 k-tiles per block

#define BARX()  __builtin_amdgcn_s_barrier()
#define SB0()   __builtin_amdgcn_sched_barrier(0)
#define LGKM(N) asm volatile("s_waitcnt lgkmcnt(" #N ")" ::: "memory")
#define VMC(N)  asm volatile("s_waitcnt vmcnt(" #N ")" ::: "memory")

__global__ __launch_bounds__(512, 2) void gemm_bf16_kernel(
    const unsigned short* __restrict__ A,   // [E*2048][1024] bf16
    const unsigned short* __restrict__ B,   // [E*4096][1024] bf16 (W^T)
    float* __restrict__ C)                  // [E*2048][4096] fp32
{
    const int bid = blockIdx.x;   // 0..255, 1 block/CU (128 KiB LDS)
    const int x   = bid & 7;      // XCD chunk: each XCD owns a contiguous swz range
    const int sl  = bid >> 3;     // 0..31

    const int tid  = threadIdx.x;
    const int lane = tid & 63;
    const int wid  = tid >> 6;
    const int wm   = wid >> 2;
    const int wn   = wid & 3;
    const int lrow = lane & 15;
    const int kq   = lane >> 4;

    __shared__ __align__(16) unsigned short sA[2][GBM * GBK];
    __shared__ __align__(16) unsigned short sB[2][GBN * GBK];

    // Involution swizzle (conflict-free, verified R3): phys_slot = chunk ^ (row&7);
    // gload_lds writes linearly so the global source pre-applies the inverse.
    const int schunk = (lane & 7) ^ ((lane >> 3) & 7);
    const int srow   = lane >> 3;

    const unsigned short *Acur, *Bcur, *Anext, *Bnext;
    float* Ccur;
    int jj = 0;

    auto setBasesAB = [&](int j, const unsigned short*& Ab, const unsigned short*& Bb) {
        int swz = x * 256 + j * 32 + sl;
        int e = swz >> 7, rem = swz & 127, bm = rem >> 4, bn = rem & 15;
        Ab = A + ((size_t)e * M_PER_E + (size_t)bm * GBM) * K_DIM;
        Bb = B + ((size_t)e * N_DIM  + (size_t)bn * GBN) * K_DIM;
    };
    auto setBaseC = [&](int j) {
        int swz = x * 256 + j * 32 + sl;
        int e = swz >> 7, rem = swz & 127, bm = rem >> 4, bn = rem & 15;
        Ccur = C + ((size_t)e * M_PER_E + (size_t)bm * GBM) * N_DIM + (size_t)bn * GBN;
    };

    // stage one A quarter (64 rows, 1 load/thread) of global k-tile g
    auto STAGE_AQ = [&](int g, int q) {
        if (g >= NT_TOTAL) return;
        const unsigned short* base = ((g >> 4) == jj) ? Acur : Anext;
        const unsigned short* src = base + (size_t)(q * 64 + wid * 8 + srow) * K_DIM
                                    + (g & 15) * GBK + schunk * 8;
        __builtin_amdgcn_global_load_lds(
            (const __attribute__((address_space(1))) void*)src,
            (__attribute__((address_space(3))) void*)&sA[g & 1][(q * 64 + wid * 8) * GBK],
            16, 0, 0);
    };
    // stage one B half (128 rows, 2 loads/thread)
    auto STAGE_BH = [&](int g, int h) {
        if (g >= NT_TOTAL) return;
        const unsigned short* base = ((g >> 4) == jj) ? Bcur : Bnext;
#pragma unroll
        for (int j2 = 0; j2 < 2; ++j2) {
            int rb = h * 128 + (wid * 2 + j2) * 8;
            const unsigned short* src = base + (size_t)(rb + srow) * K_DIM
                                        + (g & 15) * GBK + schunk * 8;
            __builtin_amdgcn_global_load_lds(
                (const __attribute__((address_space(1))) void*)src,
                (__attribute__((address_space(3))) void*)&sB[g & 1][rb * GBK],
                16, 0, 0);
        }
    };

    f32x4 acc[8][4];
#pragma unroll
    for (int mf = 0; mf < 8; ++mf)
#pragma unroll
        for (int nf = 0; nf < 4; ++nf) acc[mf][nf] = (f32x4)0.0f;

    bf16x8 afP[4], afQ[4], bfP[4], bfQ[4];

    auto READ_AF = [&](bf16x8* dst, int p, int mh, int s) {
        const int slot = (s * 4 + kq) ^ (lrow & 7);
#pragma unroll
        for (int mf = 0; mf < 4; ++mf) {
            int row = wm * 128 + mh * 64 + mf * 16 + lrow;
            dst[mf] = *reinterpret_cast<const bf16x8*>(&sA[p][row * GBK + slot * 8]);
        }
    };
    auto READ_BF = [&](bf16x8* dst, int p, int s) {
        const int slot = (s * 4 + kq) ^ (lrow & 7);
#pragma unroll
        for (int nf = 0; nf < 4; ++nf) {
            int row = wn * 64 + nf * 16 + lrow;
            dst[nf] = *reinterpret_cast<const bf16x8*>(&sB[p][row * GBK + slot * 8]);
        }
    };
    auto MMQ = [&](const bf16x8* af, const bf16x8* bf, int mh) {
        __builtin_amdgcn_s_setprio(1);
#pragma unroll
        for (int nf = 0; nf < 4; ++nf)
#pragma unroll
            for (int mf = 0; mf < 4; ++mf)
                acc[mh * 4 + mf][nf] = __builtin_amdgcn_mfma_f32_16x16x32_bf16(
                    af[mf], bf[nf], acc[mh * 4 + mf][nf], 0, 0, 0);
        __builtin_amdgcn_s_setprio(0);
    };

    // ---- prologue: tile0 A+B, tile1 B; pre-read first operands
    setBasesAB(0, Acur, Bcur);
    setBasesAB(1, Anext, Bnext);
    setBaseC(0);
    STAGE_AQ(0, 0); STAGE_AQ(0, 1); STAGE_AQ(0, 2); STAGE_AQ(0, 3);
    STAGE_BH(0, 0); STAGE_BH(0, 1);
    STAGE_BH(1, 0); STAGE_BH(1, 1);
    VMC(4);          // tile0 (first 8 loads) landed; B(1)'s 4 may fly
    BARX();
    READ_AF(afP, 0, 0, 0);   // af(0,mh0,s0)
    READ_BF(bfP, 0, 0);      // bf(0,s0)

#pragma unroll 1
    for (jj = 0; jj < 8; ++jj) {
        if (jj) {
            setBasesAB(jj, Acur, Bcur);
            int jn = (jj < 7) ? jj + 1 : 7;
            setBasesAB(jn, Anext, Bnext);
            setBaseC(jj);
        }
#pragma unroll 1
        for (int i = 0; i < 8; ++i) {
            const int g = jj * 16 + 2 * i;   // even tile -> buf0; g+1 -> buf1
            // ---- A: MMQ(u,mh0,s0); pre-read af(u,mh1,s0)
            READ_AF(afQ, 0, 1, 0);
            STAGE_AQ(g + 1, 0); STAGE_AQ(g + 1, 2);
            BARX(); LGKM(4); SB0();
            MMQ(afP, bfP, 0);
            BARX();
            // ---- B: MMQ(u,mh1,s0); pre-read af(u,mh0,s1)+bf(u,s1)
            READ_AF(afP, 0, 0, 1); READ_BF(bfQ, 0, 1);
            STAGE_AQ(g + 1, 1); STAGE_AQ(g + 1, 3);
            BARX(); LGKM(8); SB0();
            MMQ(afQ, bfP, 1);
            BARX();
            // ---- C: MMQ(u,mh0,s1); pre-read af(u,mh1,s1)
            READ_AF(afQ, 0, 1, 1);
            BARX(); LGKM(4); SB0();
            MMQ(afP, bfQ, 0);
            VMC(2);   // q0,q2(g+1)@A + B(g+1)@H_prev landed
            BARX();
            // ---- D: MMQ(u,mh1,s1); pre-read af(v,mh0,s0)+bf(v,s0)
            READ_AF(afP, 1, 0, 0); READ_BF(bfP, 1, 0);
            STAGE_BH(g + 2, 0);
            BARX(); LGKM(8); SB0();
            MMQ(afQ, bfQ, 1);
            VMC(2);   // q1,q3(g+1)@B landed
            BARX();
            // ---- E: MMQ(v,mh0,s0); pre-read af(v,mh1,s0)
            READ_AF(afQ, 1, 1, 0);
            STAGE_BH(g + 2, 1);
            BARX(); LGKM(4); SB0();
            MMQ(afP, bfP, 0);
            BARX();
            // ---- F: MMQ(v,mh1,s0); pre-read af(v,mh0,s1)+bf(v,s1)
            READ_AF(afP, 1, 0, 1); READ_BF(bfQ, 1, 1);
            STAGE_AQ(g + 2, 0); STAGE_AQ(g + 2, 2);
            BARX(); LGKM(8); SB0();
            MMQ(afQ, bfP, 1);
            BARX();
            // ---- G: MMQ(v,mh0,s1); pre-read af(v,mh1,s1)
            READ_AF(afQ, 1, 1, 1);
            STAGE_AQ(g + 2, 1); STAGE_AQ(g + 2, 3);
            BARX(); LGKM(4); SB0();
            MMQ(afP, bfQ, 0);
            VMC(2);   // Bh(g+2)@D,E + q0,q2(g+2)@F landed
            BARX();
            // ---- H: MMQ(v,mh1,s1); pre-read af(u+2,mh0,s0)+bf(u+2,s0)
            if (g + 2 < NT_TOTAL) {
                READ_AF(afP, 0, 0, 0); READ_BF(bfP, 0, 0);
            }
            STAGE_BH(g + 3, 0); STAGE_BH(g + 3, 1);
            BARX();
            if (g + 2 < NT_TOTAL) { LGKM(8); } else { LGKM(0); }
            SB0();
            MMQ(afQ, bfQ, 1);
            VMC(4);   // q1,q3(g+2)@G landed; B(g+3)@H may fly
            BARX();
        }

        // ---- per-output-tile epilogue (no LDS, no barriers; pipeline keeps flying)
        // C/D layout col=lane&15, row=(lane>>4)*4+j  [m89]
#pragma unroll
        for (int mf = 0; mf < 8; ++mf) {
#pragma unroll
            for (int nf = 0; nf < 4; ++nf) {
#pragma unroll
                for (int j = 0; j < 4; ++j) {
                    int row = wm * 128 + mf * 16 + kq * 4 + j;
                    int col = wn * 64 + nf * 16 + lrow;
                    Ccur[(size_t)row * N_DIM + col] = acc[mf][nf][j];
                }
                acc[mf][nf] = (f32x4)0.0f;
            }
        }
    }
}

// ---------------- Fallback: round-1 fused kernel ----------------
#define BM 128
#define BN 128
#define BK 64
#define KT (K_DIM / BK)

__device__ __forceinline__ int swz_f(int row, int kelem) {
    return kelem ^ (((row ^ (row >> 3)) & 7) << 3);
}

__global__ __launch_bounds__(256) void grouped_gemm_fused_kernel(
    const float* __restrict__ A, const float* __restrict__ W, float* __restrict__ C)
{
    const int bn = blockIdx.x;
    const int bm = blockIdx.y;
    const int e  = blockIdx.z;
    const int tid  = threadIdx.x;
    const int lane = tid & 63;
    const int wid  = tid >> 6;
    const int wr   = wid >> 1;
    const int wc   = wid & 1;

    __shared__ __align__(16) unsigned short fA[BM * BK];
    __shared__ __align__(16) unsigned short fB[BN * BK];

    const float* Abase = A + ((size_t)e * M_PER_E + (size_t)bm * BM) * K_DIM;
    const float* Wbase = W + (size_t)e * K_DIM * N_DIM + (size_t)bn * BN;
    float*       Cbase = C + ((size_t)e * M_PER_E + (size_t)bm * BM) * N_DIM + (size_t)bn * BN;

    const int arow  = tid >> 4;
    const int acol4 = (tid & 15) * 4;
    const int bkq   = tid >> 4;
    const int bnq   = tid & 15;

    f32x4 acc[4][4];
#pragma unroll
    for (int m = 0; m < 4; ++m)
#pragma unroll
        for (int n = 0; n < 4; ++n) acc[m][n] = (f32x4)0.0f;

    float4v ra[8], rb[8];

    auto LOADT = [&](int kt) {
        const float* ap = Abase + (size_t)arow * K_DIM + kt * BK + acol4;
#pragma unroll
        for (int i = 0; i < 8; ++i)
            ra[i] = *reinterpret_cast<const float4v*>(ap + (size_t)i * 16 * K_DIM);
        const float* bp = Wbase + (size_t)(kt * BK + bkq * 4) * N_DIM + bnq * 4;
#pragma unroll
        for (int i = 0; i < 2; ++i)
#pragma unroll
            for (int r = 0; r < 4; ++r)
                rb[i * 4 + r] = *reinterpret_cast<const float4v*>(bp + (size_t)r * N_DIM + i * 64);
    };

    auto STORET = [&]() {
#pragma unroll
        for (int i = 0; i < 8; ++i) {
            int row = arow + i * 16;
            ushort4v v = cvt4_bf16(ra[i]);
            *reinterpret_cast<ushort4v*>(&fA[row * BK + swz_f(row, acol4)]) = v;
        }
#pragma unroll
        for (int i = 0; i < 2; ++i) {
#pragma unroll
            for (int j = 0; j < 4; ++j) {
                int n = (bnq + i * 16) * 4 + j;
                float4v col;
                col[0] = rb[i * 4 + 0][j];
                col[1] = rb[i * 4 + 1][j];
                col[2] = rb[i * 4 + 2][j];
                col[3] = rb[i * 4 + 3][j];
                ushort4v v = cvt4_bf16(col);
                *reinterpret_cast<ushort4v*>(&fB[n * BK + swz_f(n, bkq * 4)]) = v;
            }
        }
    };

    auto COMPUTE = [&]() {
#pragma unroll
        for (int s = 0; s < 2; ++s) {
            bf16x8 af[4], bfr[4];
            const int ke = s * 32 + (lane >> 4) * 8;
#pragma unroll
            for (int m = 0; m < 4; ++m) {
                int row = wr * 64 + m * 16 + (lane & 15);
                af[m] = *reinterpret_cast<const bf16x8*>(&fA[row * BK + swz_f(row, ke)]);
            }
#pragma unroll
            for (int n = 0; n < 4; ++n) {
                int row = wc * 64 + n * 16 + (lane & 15);
                bfr[n] = *reinterpret_cast<const bf16x8*>(&fB[row * BK + swz_f(row, ke)]);
            }
#pragma unroll
            for (int m = 0; m < 4; ++m)
#pragma unroll
                for (int n = 0; n < 4; ++n)
                    acc[m][n] = __builtin_amdgcn_mfma_f32_16x16x32_bf16(
                        af[m], bfr[n], acc[m][n], 0, 0, 0);
        }
    };

    LOADT(0);
    STORET();
    __syncthreads();
    for (int kt = 0; kt < KT; ++kt) {
        if (kt + 1 < KT) LOADT(kt + 1);
        COMPUTE();
        __syncthreads();
        if (kt + 1 < KT) STORET();
        __syncthreads();
    }

#pragma unroll
    for (int m = 0; m < 4; ++m)
#pragma unroll
        for (int n = 0; n < 4; ++n)
#pragma unroll
            for (int j = 0; j < 4; ++j) {
                int row = wr * 64 + m * 16 + (lane >> 4) * 4 + j;
                int col = wc * 64 + n * 16 + (lane & 15);
                Cbase[(size_t)row * N_DIM + col] = acc[m][n][j];
            }
}

extern "C" void kernel_launch(void* const* d_in, const int* in_sizes, int n_in,
                              void* d_out, int out_size, void* d_ws, size_t ws_size,
                              hipStream_t stream) {
    const float* A = (const float*)d_in[0];
    // d_in[1] = expert_size (static 2048 each) — unused
    const float* W = (const float*)d_in[2];
    float* out = (float*)d_out;

    if (ws_size >= WS_NEEDED) {
        unsigned short* wsA = (unsigned short*)d_ws;
        unsigned short* wsW = wsA + (size_t)A_ELEMS;

        hipLaunchKernelGGL(prepass_kernel, dim3(18432), dim3(256), 0, stream,
                           A, W, wsA, wsW);
        hipLaunchKernelGGL(gemm_bf16_kernel, dim3(256), dim3(512), 0, stream,
                           wsA, wsW, out);
    } else {
        dim3 grid(N_DIM / BN, M_PER_E / BM, E_NUM);
        hipLaunchKernelGGL(grouped_gemm_fused_kernel, grid, dim3(256), 0, stream,
                           A, W, out);
    }
}

// Round 7
// 527.043 us; speedup vs baseline: 2.4057x; 2.4057x over previous
//
#include <hip/hip_runtime.h>
#include <hip/hip_bf16.h>

// Grouped GEMM: E=16 experts, each [2048x1024] @ [1024x4096], fp32 in/out.
// Round 7:
//   Pass 1 (fused): A fp32->bf16 convert + W [K][N]->WT [N][K] bf16 transpose.
//   Pass 2 : 256x128 tile, BK=32, 48 KB LDS double buffer, 512 thr (8 waves),
//            __launch_bounds__(512,4) -> VGPR<=128 -> 2 blocks/CU so one
//            block's compute overlaps the other's barrier/prologue/epilogue
//            (m97/m114 mechanism). Simple 2-barrier loop, gload_lds w=16 with
//            4-slot involution swizzle (conflict-free), XCD-bijective swizzle.

#define E_NUM 16
#define M_PER_E 2048
#define K_DIM 1024
#define N_DIM 4096

#define A_ELEMS (E_NUM * M_PER_E * K_DIM)
#define W_ELEMS (E_NUM * K_DIM * N_DIM)
#define WS_NEEDED ((size_t)A_ELEMS * 2 + (size_t)W_ELEMS * 2)

typedef float  float4v  __attribute__((ext_vector_type(4)));
typedef float  f32x4    __attribute__((ext_vector_type(4)));
typedef short  bf16x8   __attribute__((ext_vector_type(8)));
typedef unsigned short ushort4v __attribute__((ext_vector_type(4)));
typedef unsigned short ushort8v __attribute__((ext_vector_type(8)));

__device__ __forceinline__ ushort4v cvt4_bf16(float4v f) {
    union { __bf16 h[4]; ushort4v u; } x;
#pragma unroll
    for (int j = 0; j < 4; ++j) x.h[j] = (__bf16)f[j];
    return x.u;
}

// ---------------- Pass 1: fused prepass ----------------
// blocks [0,16384): W transpose (64x64 tiles); blocks [16384,18432): A convert.
__global__ __launch_bounds__(256) void prepass_kernel(
    const float* __restrict__ A, const float* __restrict__ W,
    unsigned short* __restrict__ outA, unsigned short* __restrict__ outW)
{
    __shared__ __align__(16) float T[64 * 64];
    const int b = blockIdx.x;
    const int t = threadIdx.x;

    if (b < 16384) {
        const int nt = b & 63;
        const int kt = (b >> 6) & 15;
        const int e  = b >> 10;
        const float* Wb = W + ((size_t)e * K_DIM + (size_t)kt * 64) * N_DIM + nt * 64;

#pragma unroll
        for (int j = 0; j < 4; ++j) {
            int kl = (t >> 4) + j * 16;
            int n4 = t & 15;
            float4v v = *reinterpret_cast<const float4v*>(Wb + (size_t)kl * N_DIM + n4 * 4);
            int sp = n4 ^ ((kl >> 3) & 7);
            *reinterpret_cast<float4v*>(&T[kl * 64 + sp * 4]) = v;
        }
        __syncthreads();

#pragma unroll
        for (int c = 0; c < 2; ++c) {
            int nl = (t >> 3) + c * 32;
            int kc = t & 7;
            ushort8v v;
#pragma unroll
            for (int j = 0; j < 8; ++j) {
                int kl = kc * 8 + j;
                int sp = (nl >> 2) ^ kc;
                float f = T[kl * 64 + sp * 4 + (nl & 3)];
                union { __bf16 h; unsigned short u; } cv; cv.h = (__bf16)f;
                v[j] = cv.u;
            }
            unsigned short* dst = outW + ((size_t)e * N_DIM + (size_t)nt * 64 + nl) * K_DIM
                                  + (size_t)kt * 64 + kc * 8;
            *reinterpret_cast<ushort8v*>(dst) = v;
        }
    } else {
        const int n8 = A_ELEMS / 8;
        int idx = (b - 16384) * 256 + t;
        int stride = 2048 * 256;
        for (int i = idx; i < n8; i += stride) {
            float4v a = *reinterpret_cast<const float4v*>(A + (size_t)i * 8);
            float4v bb = *reinterpret_cast<const float4v*>(A + (size_t)i * 8 + 4);
            ushort8v v;
            ushort4v va = cvt4_bf16(a), vb = cvt4_bf16(bb);
#pragma unroll
            for (int j = 0; j < 4; ++j) { v[j] = va[j]; v[j + 4] = vb[j]; }
            *reinterpret_cast<ushort8v*>(outA + (size_t)i * 8) = v;
        }
    }
}

// ---------------- Pass 2: 256x128 bf16 GEMM, 2 blocks/CU ----------------
#define TBM 256
#define TBN 128
#define TBK 32
#define TKT (K_DIM / TBK)   // 32 K-steps

__global__ __launch_bounds__(512, 4) void gemm_bf16_kernel(
    const unsigned short* __restrict__ A,   // [E*2048][1024] bf16
    const unsigned short* __restrict__ B,   // [E*4096][1024] bf16 (W^T)
    float* __restrict__ C)                  // [E*2048][4096] fp32
{
    // XCD-bijective swizzle over 4096 blocks (4096 % 8 == 0)
    const int bid   = blockIdx.x;
    const int swzid = (bid & 7) * (4096 / 8) + (bid >> 3);
    const int e   = swzid >> 8;        // 256 tiles/expert
    const int rem = swzid & 255;
    const int bm  = rem >> 5;          // 0..7   (256-row M tiles)
    const int bn  = rem & 31;          // 0..31  (128-col N tiles)

    const int tid  = threadIdx.x;
    const int lane = tid & 63;
    const int wid  = tid >> 6;         // 0..7
    const int wm   = wid >> 1;         // 0..3  (64 rows each)
    const int wn   = wid & 1;          // 0..1  (64 cols each)
    const int lrow = lane & 15;
    const int kq   = lane >> 4;        // 0..3  (8-elem k-chunk)

    // 48 KB total: 2 bufs x (A 16KB + B 8KB) -> LDS allows 3 blocks/CU,
    // VGPR (<=128 via launch_bounds) allows 2 -> 2 blocks/CU.
    __shared__ __align__(16) unsigned short sA[2][TBM * TBK];
    __shared__ __align__(16) unsigned short sB[2][TBN * TBK];

    const unsigned short* Abase = A + ((size_t)e * M_PER_E + (size_t)bm * TBM) * K_DIM;
    const unsigned short* Bbase = B + ((size_t)e * N_DIM  + (size_t)bn * TBN) * K_DIM;
    float*                Cbase = C + ((size_t)e * M_PER_E + (size_t)bm * TBM) * N_DIM
                                    + (size_t)bn * TBN;

    // 4-slot involution swizzle for 64B LDS rows (TBK=32 bf16 = 4 x 16B slots):
    //   phys_slot = logical_chunk ^ ((row>>1)&3)
    // Banks: byte = row*64 + phys*16 -> bank = (row&1)*16 + phys*4 + word.
    // For a frag read (16 rows, fixed kq): (parity, phys) takes 8 values x2
    // lanes = 2-way = free [m136]. gload_lds writes linearly (lane l -> row
    // l>>2, slot l&3), so the global source pre-applies the inverse:
    //   logical chunk = (l&3) ^ ((l>>3)&3).
    const int schunk = (lane & 3) ^ ((lane >> 3) & 3);
    const int srow   = lane >> 2;

    auto STAGE = [&](int p, int t) {
        // A: 16 KB = 16 x 1KB loads -> 2 per wave (rows wid*32 .. +31)
#pragma unroll
        for (int g = 0; g < 2; ++g) {
            const int rb = wid * 32 + g * 16;
            const unsigned short* src = Abase + (size_t)(rb + srow) * K_DIM
                                        + t * TBK + schunk * 8;
            __builtin_amdgcn_global_load_lds(
                (const __attribute__((address_space(1))) void*)src,
                (__attribute__((address_space(3))) void*)&sA[p][rb * TBK], 16, 0, 0);
        }
        // B: 8 KB = 8 x 1KB loads -> 1 per wave (rows wid*16 .. +15)
        {
            const int rb = wid * 16;
            const unsigned short* src = Bbase + (size_t)(rb + srow) * K_DIM
                                        + t * TBK + schunk * 8;
            __builtin_amdgcn_global_load_lds(
                (const __attribute__((address_space(1))) void*)src,
                (__attribute__((address_space(3))) void*)&sB[p][rb * TBK], 16, 0, 0);
        }
    };

    f32x4 acc[4][4];
#pragma unroll
    for (int m = 0; m < 4; ++m)
#pragma unroll
        for (int n = 0; n < 4; ++n) acc[m][n] = (f32x4)0.0f;

    auto COMPUTE = [&](int p) {
        bf16x8 af[4], bfr[4];
#pragma unroll
        for (int mf = 0; mf < 4; ++mf) {
            int row = wm * 64 + mf * 16 + lrow;
            int slot = kq ^ ((row >> 1) & 3);
            af[mf] = *reinterpret_cast<const bf16x8*>(&sA[p][row * TBK + slot * 8]);
        }
#pragma unroll
        for (int nf = 0; nf < 4; ++nf) {
            int row = wn * 64 + nf * 16 + lrow;
            int slot = kq ^ ((row >> 1) & 3);
            bfr[nf] = *reinterpret_cast<const bf16x8*>(&sB[p][row * TBK + slot * 8]);
        }
#pragma unroll
        for (int nf = 0; nf < 4; ++nf)
#pragma unroll
            for (int mf = 0; mf < 4; ++mf)
                acc[mf][nf] = __builtin_amdgcn_mfma_f32_16x16x32_bf16(
                    af[mf], bfr[nf], acc[mf][nf], 0, 0, 0);
    };

    // m97-style loop: stage t+1 before compute t; single __syncthreads per
    // step (compiler drains vmcnt+lgkm before the barrier). The co-resident
    // second block on the CU hides the drain.
    STAGE(0, 0);
    __syncthreads();
    int buf = 0;
#pragma unroll 1
    for (int t = 0; t < TKT - 1; ++t) {
        STAGE(buf ^ 1, t + 1);
        COMPUTE(buf);
        __syncthreads();
        buf ^= 1;
    }
    COMPUTE(buf);

    // epilogue: C/D layout col=lane&15, row=(lane>>4)*4+j  [m89]
#pragma unroll
    for (int mf = 0; mf < 4; ++mf) {
#pragma unroll
        for (int nf = 0; nf < 4; ++nf) {
#pragma unroll
            for (int j = 0; j < 4; ++j) {
                int row = wm * 64 + mf * 16 + kq * 4 + j;
                int col = wn * 64 + nf * 16 + lrow;
                Cbase[(size_t)row * N_DIM + col] = acc[mf][nf][j];
            }
        }
    }
}

// ---------------- Fallback: round-1 fused kernel ----------------
#define BM 128
#define BN 128
#define BK 64
#define KT (K_DIM / BK)

__device__ __forceinline__ int swz_f(int row, int kelem) {
    return kelem ^ (((row ^ (row >> 3)) & 7) << 3);
}

__global__ __launch_bounds__(256) void grouped_gemm_fused_kernel(
    const float* __restrict__ A, const float* __restrict__ W, float* __restrict__ C)
{
    const int bn = blockIdx.x;
    const int bm = blockIdx.y;
    const int e  = blockIdx.z;
    const int tid  = threadIdx.x;
    const int lane = tid & 63;
    const int wid  = tid >> 6;
    const int wr   = wid >> 1;
    const int wc   = wid & 1;

    __shared__ __align__(16) unsigned short fA[BM * BK];
    __shared__ __align__(16) unsigned short fB[BN * BK];

    const float* Abase = A + ((size_t)e * M_PER_E + (size_t)bm * BM) * K_DIM;
    const float* Wbase = W + (size_t)e * K_DIM * N_DIM + (size_t)bn * BN;
    float*       Cbase = C + ((size_t)e * M_PER_E + (size_t)bm * BM) * N_DIM + (size_t)bn * BN;

    const int arow  = tid >> 4;
    const int acol4 = (tid & 15) * 4;
    const int bkq   = tid >> 4;
    const int bnq   = tid & 15;

    f32x4 acc[4][4];
#pragma unroll
    for (int m = 0; m < 4; ++m)
#pragma unroll
        for (int n = 0; n < 4; ++n) acc[m][n] = (f32x4)0.0f;

    float4v ra[8], rb[8];

    auto LOADT = [&](int kt) {
        const float* ap = Abase + (size_t)arow * K_DIM + kt * BK + acol4;
#pragma unroll
        for (int i = 0; i < 8; ++i)
            ra[i] = *reinterpret_cast<const float4v*>(ap + (size_t)i * 16 * K_DIM);
        const float* bp = Wbase + (size_t)(kt * BK + bkq * 4) * N_DIM + bnq * 4;
#pragma unroll
        for (int i = 0; i < 2; ++i)
#pragma unroll
            for (int r = 0; r < 4; ++r)
                rb[i * 4 + r] = *reinterpret_cast<const float4v*>(bp + (size_t)r * N_DIM + i * 64);
    };

    auto STORET = [&]() {
#pragma unroll
        for (int i = 0; i < 8; ++i) {
            int row = arow + i * 16;
            ushort4v v = cvt4_bf16(ra[i]);
            *reinterpret_cast<ushort4v*>(&fA[row * BK + swz_f(row, acol4)]) = v;
        }
#pragma unroll
        for (int i = 0; i < 2; ++i) {
#pragma unroll
            for (int j = 0; j < 4; ++j) {
                int n = (bnq + i * 16) * 4 + j;
                float4v col;
                col[0] = rb[i * 4 + 0][j];
                col[1] = rb[i * 4 + 1][j];
                col[2] = rb[i * 4 + 2][j];
                col[3] = rb[i * 4 + 3][j];
                ushort4v v = cvt4_bf16(col);
                *reinterpret_cast<ushort4v*>(&fB[n * BK + swz_f(n, bkq * 4)]) = v;
            }
        }
    };

    auto COMPUTE = [&]() {
#pragma unroll
        for (int s = 0; s < 2; ++s) {
            bf16x8 af[4], bfr[4];
            const int ke = s * 32 + (lane >> 4) * 8;
#pragma unroll
            for (int m = 0; m < 4; ++m) {
                int row = wr * 64 + m * 16 + (lane & 15);
                af[m] = *reinterpret_cast<const bf16x8*>(&fA[row * BK + swz_f(row, ke)]);
            }
#pragma unroll
            for (int n = 0; n < 4; ++n) {
                int row = wc * 64 + n * 16 + (lane & 15);
                bfr[n] = *reinterpret_cast<const bf16x8*>(&fB[row * BK + swz_f(row, ke)]);
            }
#pragma unroll
            for (int m = 0; m < 4; ++m)
#pragma unroll
                for (int n = 0; n < 4; ++n)
                    acc[m][n] = __builtin_amdgcn_mfma_f32_16x16x32_bf16(
                        af[m], bfr[n], acc[m][n], 0, 0, 0);
        }
    };

    LOADT(0);
    STORET();
    __syncthreads();
    for (int kt = 0; kt < KT; ++kt) {
        if (kt + 1 < KT) LOADT(kt + 1);
        COMPUTE();
        __syncthreads();
        if (kt + 1 < KT) STORET();
        __syncthreads();
    }

#pragma unroll
    for (int m = 0; m < 4; ++m)
#pragma unroll
        for (int n = 0; n < 4; ++n)
#pragma unroll
            for (int j = 0; j < 4; ++j) {
                int row = wr * 64 + m * 16 + (lane >> 4) * 4 + j;
                int col = wc * 64 + n * 16 + (lane & 15);
                Cbase[(size_t)row * N_DIM + col] = acc[m][n][j];
            }
}

extern "C" void kernel_launch(void* const* d_in, const int* in_sizes, int n_in,
                              void* d_out, int out_size, void* d_ws, size_t ws_size,
                              hipStream_t stream) {
    const float* A = (const float*)d_in[0];
    // d_in[1] = expert_size (static 2048 each) — unused
    const float* W = (const float*)d_in[2];
    float* out = (float*)d_out;

    if (ws_size >= WS_NEEDED) {
        unsigned short* wsA = (unsigned short*)d_ws;
        unsigned short* wsW = wsA + (size_t)A_ELEMS;

        hipLaunchKernelGGL(prepass_kernel, dim3(18432), dim3(256), 0, stream,
                           A, W, wsA, wsW);
        hipLaunchKernelGGL(gemm_bf16_kernel, dim3(4096), dim3(512), 0, stream,
                           wsA, wsW, out);
    } else {
        dim3 grid(N_DIM / BN, M_PER_E / BM, E_NUM);
        hipLaunchKernelGGL(grouped_gemm_fused_kernel, grid, dim3(256), 0, stream,
                           A, W, out);
    }
}